// Round 10
// baseline (1156.332 us; speedup 1.0000x reference)
//
#include <hip/hip_runtime.h>
#include <math.h>

#define B_      4
#define T_      20
#define N_      256
#define L_      5120      // T_*N_
#define CC_     32
#define CMAP_   2048
#define HW_     256       // 16*16
#define GRID_   1280      // 20 groups of 64
#define MSPLIT_ 64
#define MCHUNK_ 80        // L_/MSPLIT_
#define CSPL_   32        // compress channel splits
#define CW_     64        // channels per split (CMAP_/CSPL_)

__device__ __forceinline__ float fexp2(float x) { return __builtin_amdgcn_exp2f(x); }
__device__ __forceinline__ float frcp(float x)  { return __builtin_amdgcn_rcpf(x); }
__device__ __forceinline__ float sigm(float x)  { return frcp(1.f + fexp2(-1.44269504f * x)); }
__device__ __forceinline__ float tanh_(float x) { return 1.f - 2.f * frcp(fexp2(2.88539008f * x) + 1.f); }

// two-level grid barrier: 20 group counters (64 blocks each) -> root -> gen flag.
// counters live in ws (zeroed by hipMemsetAsync each launch), 64B-strided.
__device__ __forceinline__ void gbar(unsigned* cnt, unsigned* gen) {
    __syncthreads();
    if (threadIdx.x == 0) {
        __threadfence();   // release this block's writes (agent scope)
        unsigned g = __hip_atomic_load(gen, __ATOMIC_RELAXED, __HIP_MEMORY_SCOPE_AGENT);
        int grp = blockIdx.x >> 6;   // [0,20)
        unsigned prev = __hip_atomic_fetch_add(&cnt[grp * 16], 1u,
                                               __ATOMIC_ACQ_REL, __HIP_MEMORY_SCOPE_AGENT);
        if (prev == 63u) {
            unsigned pr = __hip_atomic_fetch_add(&cnt[32 * 16], 1u,
                                                 __ATOMIC_ACQ_REL, __HIP_MEMORY_SCOPE_AGENT);
            if (pr == 19u) {   // last block of all: reset counters, release next generation
                #pragma unroll
                for (int i = 0; i < 33; ++i)
                    __hip_atomic_store(&cnt[i * 16], 0u, __ATOMIC_RELAXED, __HIP_MEMORY_SCOPE_AGENT);
                __hip_atomic_store(gen, g + 1u, __ATOMIC_RELEASE, __HIP_MEMORY_SCOPE_AGENT);
            } else {
                while (__hip_atomic_load(gen, __ATOMIC_ACQUIRE, __HIP_MEMORY_SCOPE_AGENT) == g)
                    __builtin_amdgcn_s_sleep(2);
            }
        } else {
            while (__hip_atomic_load(gen, __ATOMIC_ACQUIRE, __HIP_MEMORY_SCOPE_AGENT) == g)
                __builtin_amdgcn_s_sleep(2);
        }
        __threadfence();   // acquire side
    }
    __syncthreads();
}

// ws float layout:
//  [0,1152)                  barrier counters/gen (only first ~2.2KB used)
//  pcm  @1152    size 32*4*32*256 = 1048576
//  cm   @1049728 size 32768
//  ABC  @1082496 size 4*B*L = 81920   (float4 per token, -log2e pre-scaled)
//  XM   @1164416 size 2*B*L = 40960   (float2 per token)
//  part @1205376 size MSPLIT*B*L*4 = 5242880
// total 6448256 floats = 25.8 MB

__global__ void __launch_bounds__(256, 5) k_fused(
        const float* __restrict__ x,      const float* __restrict__ md,
        const float* __restrict__ w_ih,   const float* __restrict__ b_ih,
        const float* __restrict__ b_hh,
        const float* __restrict__ comp_w, const float* __restrict__ comp_b,
        const float* __restrict__ vf_w,   const float* __restrict__ vf_b,
        const float* __restrict__ fc_w,   const float* __restrict__ fc_b,
        const float* __restrict__ fc2_w,  const float* __restrict__ fc2_b,
        const float* __restrict__ fc3_w,  const float* __restrict__ fc3_b,
        const float* __restrict__ fco_w,  const float* __restrict__ fco_b,
        float* __restrict__ ws, float* __restrict__ out) {
    __shared__ float xs[2 * MCHUNK_];   // attn XM stage (640 B)
    unsigned* cnt = (unsigned*)ws;
    unsigned* gen = cnt + 33 * 16;
    float* pcm  = ws + 1152;
    float* cm   = pcm + CSPL_ * B_ * CC_ * HW_;
    float* ABC  = cm + B_ * CC_ * HW_;
    float* XM   = ABC + 4 * B_ * L_;
    float* part = XM + 2 * B_ * L_;

    int blk = blockIdx.x, tid = threadIdx.x;

    // ---- Phase A: compressor partials. 128 blocks (b,cs); thread = hw ----
    if (blk < B_ * CSPL_) {
        int cs = blk & (CSPL_ - 1);
        int b  = blk >> 5;
        int c0 = cs * CW_;
        const float* mp = md + ((size_t)(b * CMAP_ + c0)) * HW_ + tid;
        const float* wp = comp_w + c0;   // weights: uniform addresses -> scalar loads
        float a[CC_];
        #pragma unroll
        for (int o = 0; o < CC_; ++o) a[o] = 0.f;
        for (int cc = 0; cc < CW_; ++cc) {
            float mv = mp[(size_t)cc * HW_];   // fully coalesced 1KB/wave
            #pragma unroll
            for (int o = 0; o < CC_; ++o)
                a[o] = fmaf(wp[o * CMAP_ + cc], mv, a[o]);
        }
        float* pp = pcm + (size_t)(cs * B_ + b) * (CC_ * HW_) + tid;
        #pragma unroll
        for (int o = 0; o < CC_; ++o) pp[o * HW_] = a[o];
    }
    gbar(cnt, gen);

    // ---- Phase A2: reduce 32 c-splits + bias -> cm. 128 blocks ----
    if (blk < 128) {
        int i = blk * 256 + tid;   // [0, 32768) = ((b*32+o)*256+hw)
        float s = comp_b[(i >> 8) & 31];
        #pragma unroll
        for (int ps = 0; ps < CSPL_; ++ps) s += pcm[ps * (B_ * CC_ * HW_) + i];
        cm[i] = s;
    }
    gbar(cnt, gen);

    // ---- Phase B: per-token LSTM + grid-sample + projections. 80 blocks ----
    if (blk < 80) {
        int p = blk * 256 + tid;   // [0, B*L)
        int b = p / L_;
        int l = p - b * L_;
        int t = l >> 8, n = l & 255;
        float x0r = x[((b * 2 + 0) * T_ + t) * N_ + n];
        float x1r = x[((b * 2 + 1) * T_ + t) * N_ + n];
        float xr0 = x0r + sinf((float)t);
        float xr1 = x1r + cosf((float)t);
        float Xh[4];
        #pragma unroll
        for (int k = 0; k < 4; ++k) {
            float ig = w_ih[(k)      * 2] * xr0 + w_ih[(k)      * 2 + 1] * xr1 + b_ih[k]      + b_hh[k];
            float gg = w_ih[(8 + k)  * 2] * xr0 + w_ih[(8 + k)  * 2 + 1] * xr1 + b_ih[8 + k]  + b_hh[8 + k];
            float og = w_ih[(12 + k) * 2] * xr0 + w_ih[(12 + k) * 2 + 1] * xr1 + b_ih[12 + k] + b_hh[12 + k];
            float c = sigm(ig) * tanh_(gg);
            Xh[k] = sigm(og) * tanh_(c);
        }
        // bilinear grid-sample on RAW coords (align_corners=False, zero pad)
        float ix = x0r * 0.03125f - 0.5f;
        float iy = x1r * 0.03125f - 0.5f;
        float x0f = floorf(ix), y0f = floorf(iy);
        float wx1 = ix - x0f, wx0 = 1.f - wx1;
        float wy1 = iy - y0f, wy0 = 1.f - wy1;
        int x0 = (int)x0f, y0 = (int)y0f;
        int x1 = x0 + 1, y1 = y0 + 1;
        bool vx0 = (x0 >= 0) && (x0 <= 15), vx1 = (x1 >= 0) && (x1 <= 15);
        bool vy0 = (y0 >= 0) && (y0 <= 15), vy1 = (y1 >= 0) && (y1 <= 15);
        int cx0 = min(max(x0, 0), 15), cx1 = min(max(x1, 0), 15);
        int cy0 = min(max(y0, 0), 15), cy1 = min(max(y1, 0), 15);
        float wg0 = (vx0 && vy0) ? wx0 * wy0 : 0.f; int of0 = cy0 * 16 + cx0;
        float wg1 = (vx1 && vy0) ? wx1 * wy0 : 0.f; int of1 = cy0 * 16 + cx1;
        float wg2 = (vx0 && vy1) ? wx0 * wy1 : 0.f; int of2 = cy1 * 16 + cx0;
        float wg3 = (vx1 && vy1) ? wx1 * wy1 : 0.f; int of3 = cy1 * 16 + cx1;
        float X2[4];
        #pragma unroll
        for (int j = 0; j < 4; ++j)
            X2[j] = vf_b[j] + vf_w[j * 36 + 0] * Xh[0] + vf_w[j * 36 + 1] * Xh[1]
                            + vf_w[j * 36 + 2] * Xh[2] + vf_w[j * 36 + 3] * Xh[3];
        const float* cmb = cm + (size_t)b * CC_ * HW_;
        #pragma unroll 8
        for (int c = 0; c < 32; ++c) {
            const float* pch = cmb + c * HW_;
            float lc = wg0 * pch[of0] + wg1 * pch[of1] + wg2 * pch[of2] + wg3 * pch[of3];
            #pragma unroll
            for (int j = 0; j < 4; ++j) X2[j] += vf_w[j * 36 + 4 + c] * lc;
        }
        float A = 0.f, Bv = 0.f, C = 0.f;
        #pragma unroll
        for (int j = 0; j < 8; ++j) {
            float Qj = fc_b[j] + fc_w[j * 4 + 0] * X2[0] + fc_w[j * 4 + 1] * X2[1]
                               + fc_w[j * 4 + 2] * X2[2] + fc_w[j * 4 + 3] * X2[3];
            A  += Qj * fc2_w[j * 2 + 0];
            Bv += Qj * fc2_w[j * 2 + 1];
            C  += Qj * fc2_b[j];
        }
        const float NLG2E = -1.44269504f;   // fold sigmoid's -log2(e) into coeffs
        ((float4*)ABC)[p] = make_float4(NLG2E * A, NLG2E * Bv, NLG2E * C, 0.f);
        ((float2*)XM)[p]  = make_float2(xr0, xr1);
    }
    gbar(cnt, gen);

    // ---- Phase C: rank-2 sigmoid attention, all 1280 blocks ----
    {
        int ms = blk & (MSPLIT_ - 1);
        int rest = blk >> 6;        // [0,20)
        int lt = rest % 5, b = rest / 5;
        // stage this block's XM chunk (80 float2) into LDS
        const float* xp = XM + 2 * ((size_t)b * L_ + ms * MCHUNK_);
        for (int i = tid; i < 2 * MCHUNK_; i += 256) xs[i] = xp[i];
        float A[4], Bv[4], C[4], S0[4], S1[4], Sp[4];
        #pragma unroll
        for (int k = 0; k < 4; ++k) {
            int l = lt * 1024 + k * 256 + tid;
            float4 abc = ((const float4*)ABC)[(size_t)b * L_ + l];
            A[k] = abc.x; Bv[k] = abc.y; C[k] = abc.z;
            S0[k] = 0.f; S1[k] = 0.f; Sp[k] = 0.f;
        }
        __syncthreads();
        #pragma unroll 4
        for (int j = 0; j < MCHUNK_; ++j) {
            float x0 = xs[2 * j], x1 = xs[2 * j + 1];   // LDS broadcast
            #pragma unroll
            for (int k = 0; k < 4; ++k) {
                float e = fexp2(fmaf(A[k], x0, fmaf(Bv[k], x1, C[k])));
                float pb = frcp(1.f + e);
                S0[k] = fmaf(pb, x0, S0[k]);
                S1[k] = fmaf(pb, x1, S1[k]);
                Sp[k] += pb;
            }
        }
        #pragma unroll
        for (int k = 0; k < 4; ++k) {
            int l = lt * 1024 + k * 256 + tid;
            ((float4*)part)[(size_t)(ms * B_ + b) * L_ + l] =
                make_float4(S0[k], S1[k], Sp[k], 0.f);
        }
    }
    gbar(cnt, gen);

    // ---- Phase D: reduce partials + V-reconstruct + trelu + fco. 80 blocks ----
    if (blk < 80) {
        int p = blk * 256 + tid;
        int b = p / L_, l = p - b * L_;
        float s0 = 0.f, s1 = 0.f, sp = 0.f;
        for (int s = 0; s < MSPLIT_; ++s) {
            float4 u = ((const float4*)part)[(size_t)(s * B_ + b) * L_ + l];
            s0 += u.x; s1 += u.y; sp += u.z;
        }
        float o0 = fco_b[0], o1 = fco_b[1];
        #pragma unroll
        for (int d = 0; d < 8; ++d) {
            float od = fc3_w[d * 2 + 0] * s0 + fc3_w[d * 2 + 1] * s1 + fc3_b[d] * sp;
            od = od > 0.5f ? od : 0.f;   // threshold_relu, TH=0.5
            o0 += fco_w[d] * od;
            o1 += fco_w[8 + d] * od;
        }
        int t = l >> 8, n = l & 255;
        out[((b * 2 + 0) * T_ + t) * N_ + n] = o0;
        out[((b * 2 + 1) * T_ + t) * N_ + n] = o1;
    }
}

extern "C" void kernel_launch(void* const* d_in, const int* in_sizes, int n_in,
                              void* d_out, int out_size, void* d_ws, size_t ws_size,
                              hipStream_t stream) {
    const float* x      = (const float*)d_in[0];
    const float* md     = (const float*)d_in[1];
    const float* w_ih   = (const float*)d_in[2];
    const float* b_ih   = (const float*)d_in[3];
    const float* b_hh   = (const float*)d_in[4];
    const float* comp_w = (const float*)d_in[5];
    const float* comp_b = (const float*)d_in[6];
    const float* vf_w   = (const float*)d_in[7];
    const float* vf_b   = (const float*)d_in[8];
    const float* fc_w   = (const float*)d_in[9];
    const float* fc_b   = (const float*)d_in[10];
    const float* fc2_w  = (const float*)d_in[11];
    const float* fc2_b  = (const float*)d_in[12];
    const float* fc3_w  = (const float*)d_in[13];
    const float* fc3_b  = (const float*)d_in[14];
    const float* fco_w  = (const float*)d_in[15];
    const float* fco_b  = (const float*)d_in[16];

    // zero the grid-barrier counters (captured as a graph memset node)
    hipMemsetAsync(d_ws, 0, 4608, stream);
    hipLaunchKernelGGL(k_fused, dim3(GRID_), dim3(256), 0, stream,
                       x, md, w_ih, b_ih, b_hh, comp_w, comp_b,
                       vf_w, vf_b, fc_w, fc_b, fc2_w, fc2_b,
                       fc3_w, fc3_b, fco_w, fco_b,
                       (float*)d_ws, (float*)d_out);
}

// Round 11
// 272.155 us; speedup vs baseline: 4.2488x; 4.2488x over previous
//
#include <hip/hip_runtime.h>
#include <math.h>

#define B_      4
#define T_      20
#define N_      256
#define L_      5120      // T_*N_
#define CC_     32
#define CMAP_   2048
#define HW_     256       // 16*16
#define GRID_   1280      // 20 groups of 64
#define MSPLIT_ 64
#define MCHUNK_ 80        // L_/MSPLIT_
#define CSPL_   32        // compress channel splits
#define CW_     64        // channels per split (CMAP_/CSPL_)

__device__ __forceinline__ float fexp2(float x) { return __builtin_amdgcn_exp2f(x); }
__device__ __forceinline__ float frcp(float x)  { return __builtin_amdgcn_rcpf(x); }
__device__ __forceinline__ float sigm(float x)  { return frcp(1.f + fexp2(-1.44269504f * x)); }
__device__ __forceinline__ float tanh_(float x) { return 1.f - 2.f * frcp(fexp2(2.88539008f * x) + 1.f); }

// ---- grid barrier v2: relaxed polls + one fence per block per barrier ----
// Lesson from R10: per-poll ACQUIRE at agent scope = L1/L2 invalidate per
// iteration x 1280 spinners -> ~270us/barrier. v2: RELAXED polls (LLC reads),
// exactly one release fence (wbL2) before arrival and one acquire fence
// (inv) after release is observed. Fence-fence sync gives transitivity.
__device__ __forceinline__ void gbar(unsigned* cnt, unsigned* gen) {
    __syncthreads();   // compiler emits vmcnt(0) drain: block's stores are in L2
    if (threadIdx.x == 0) {
        __builtin_amdgcn_fence(__ATOMIC_RELEASE, "agent");   // wbL2 once
        unsigned g = __hip_atomic_load(gen, __ATOMIC_RELAXED, __HIP_MEMORY_SCOPE_AGENT);
        int grp = blockIdx.x >> 6;   // [0,20)
        unsigned prev = __hip_atomic_fetch_add(&cnt[grp * 16], 1u,
                                               __ATOMIC_RELAXED, __HIP_MEMORY_SCOPE_AGENT);
        if (prev == 63u) {
            // group root: syncs with group members' release fences
            __builtin_amdgcn_fence(__ATOMIC_ACQUIRE, "agent");
            unsigned pr = __hip_atomic_fetch_add(&cnt[32 * 16], 1u,
                                                 __ATOMIC_RELAXED, __HIP_MEMORY_SCOPE_AGENT);
            if (pr == 19u) {   // global last: sync, reset, publish next generation
                __builtin_amdgcn_fence(__ATOMIC_ACQUIRE, "agent");
                #pragma unroll
                for (int i = 0; i < 33; ++i)
                    __hip_atomic_store(&cnt[i * 16], 0u, __ATOMIC_RELAXED, __HIP_MEMORY_SCOPE_AGENT);
                // RELEASE store orders the resets (and everything) before gen flip
                __hip_atomic_store(gen, g + 1u, __ATOMIC_RELEASE, __HIP_MEMORY_SCOPE_AGENT);
            } else {
                while (__hip_atomic_load(gen, __ATOMIC_RELAXED, __HIP_MEMORY_SCOPE_AGENT) == g)
                    __builtin_amdgcn_s_sleep(16);
                __builtin_amdgcn_fence(__ATOMIC_ACQUIRE, "agent");
            }
        } else {
            while (__hip_atomic_load(gen, __ATOMIC_RELAXED, __HIP_MEMORY_SCOPE_AGENT) == g)
                __builtin_amdgcn_s_sleep(16);
            __builtin_amdgcn_fence(__ATOMIC_ACQUIRE, "agent");
        }
    }
    __syncthreads();
}

// ws float layout:
//  [0,1152)                  barrier counters/gen
//  pcm  @1152    size 32*4*32*256 = 1048576
//  cm   @1049728 size 32768
//  ABC  @1082496 size 4*B*L = 81920   (float4 per token, -log2e pre-scaled)
//  XM   @1164416 size 2*B*L = 40960   (float2 per token)
//  part @1205376 size MSPLIT*B*L*4 = 5242880
// total 6448256 floats = 25.8 MB

__global__ void __launch_bounds__(256, 5) k_fused(
        const float* __restrict__ x,      const float* __restrict__ md,
        const float* __restrict__ w_ih,   const float* __restrict__ b_ih,
        const float* __restrict__ b_hh,
        const float* __restrict__ comp_w, const float* __restrict__ comp_b,
        const float* __restrict__ vf_w,   const float* __restrict__ vf_b,
        const float* __restrict__ fc_w,   const float* __restrict__ fc_b,
        const float* __restrict__ fc2_w,  const float* __restrict__ fc2_b,
        const float* __restrict__ fc3_w,  const float* __restrict__ fc3_b,
        const float* __restrict__ fco_w,  const float* __restrict__ fco_b,
        float* __restrict__ ws, float* __restrict__ out) {
    __shared__ float xs[2 * MCHUNK_];   // attn XM stage (640 B)
    unsigned* cnt = (unsigned*)ws;
    unsigned* gen = cnt + 33 * 16;
    float* pcm  = ws + 1152;
    float* cm   = pcm + CSPL_ * B_ * CC_ * HW_;
    float* ABC  = cm + B_ * CC_ * HW_;
    float* XM   = ABC + 4 * B_ * L_;
    float* part = XM + 2 * B_ * L_;

    int blk = blockIdx.x, tid = threadIdx.x;

    // ---- Phase A: compressor partials. 128 blocks (b,cs); thread = hw ----
    if (blk < B_ * CSPL_) {
        int cs = blk & (CSPL_ - 1);
        int b  = blk >> 5;
        int c0 = cs * CW_;
        const float* mp = md + ((size_t)(b * CMAP_ + c0)) * HW_ + tid;
        const float* wp = comp_w + c0;   // uniform addresses -> scalar loads
        float a[CC_];
        #pragma unroll
        for (int o = 0; o < CC_; ++o) a[o] = 0.f;
        for (int cc = 0; cc < CW_; ++cc) {
            float mv = mp[(size_t)cc * HW_];   // fully coalesced 1KB/wave
            #pragma unroll
            for (int o = 0; o < CC_; ++o)
                a[o] = fmaf(wp[o * CMAP_ + cc], mv, a[o]);
        }
        float* pp = pcm + (size_t)(cs * B_ + b) * (CC_ * HW_) + tid;
        #pragma unroll
        for (int o = 0; o < CC_; ++o) pp[o * HW_] = a[o];
    }
    gbar(cnt, gen);

    // ---- Phase A2: reduce 32 c-splits + bias -> cm. 128 blocks ----
    if (blk < 128) {
        int i = blk * 256 + tid;   // [0, 32768) = ((b*32+o)*256+hw)
        float s = comp_b[(i >> 8) & 31];
        #pragma unroll
        for (int ps = 0; ps < CSPL_; ++ps) s += pcm[ps * (B_ * CC_ * HW_) + i];
        cm[i] = s;
    }
    gbar(cnt, gen);

    // ---- Phase B: per-token LSTM + grid-sample + projections. 80 blocks ----
    if (blk < 80) {
        int p = blk * 256 + tid;   // [0, B*L)
        int b = p / L_;
        int l = p - b * L_;
        int t = l >> 8, n = l & 255;
        float x0r = x[((b * 2 + 0) * T_ + t) * N_ + n];
        float x1r = x[((b * 2 + 1) * T_ + t) * N_ + n];
        float xr0 = x0r + sinf((float)t);
        float xr1 = x1r + cosf((float)t);
        float Xh[4];
        #pragma unroll
        for (int k = 0; k < 4; ++k) {
            float ig = w_ih[(k)      * 2] * xr0 + w_ih[(k)      * 2 + 1] * xr1 + b_ih[k]      + b_hh[k];
            float gg = w_ih[(8 + k)  * 2] * xr0 + w_ih[(8 + k)  * 2 + 1] * xr1 + b_ih[8 + k]  + b_hh[8 + k];
            float og = w_ih[(12 + k) * 2] * xr0 + w_ih[(12 + k) * 2 + 1] * xr1 + b_ih[12 + k] + b_hh[12 + k];
            float c = sigm(ig) * tanh_(gg);
            Xh[k] = sigm(og) * tanh_(c);
        }
        // bilinear grid-sample on RAW coords (align_corners=False, zero pad)
        float ix = x0r * 0.03125f - 0.5f;
        float iy = x1r * 0.03125f - 0.5f;
        float x0f = floorf(ix), y0f = floorf(iy);
        float wx1 = ix - x0f, wx0 = 1.f - wx1;
        float wy1 = iy - y0f, wy0 = 1.f - wy1;
        int x0 = (int)x0f, y0 = (int)y0f;
        int x1 = x0 + 1, y1 = y0 + 1;
        bool vx0 = (x0 >= 0) && (x0 <= 15), vx1 = (x1 >= 0) && (x1 <= 15);
        bool vy0 = (y0 >= 0) && (y0 <= 15), vy1 = (y1 >= 0) && (y1 <= 15);
        int cx0 = min(max(x0, 0), 15), cx1 = min(max(x1, 0), 15);
        int cy0 = min(max(y0, 0), 15), cy1 = min(max(y1, 0), 15);
        float wg0 = (vx0 && vy0) ? wx0 * wy0 : 0.f; int of0 = cy0 * 16 + cx0;
        float wg1 = (vx1 && vy0) ? wx1 * wy0 : 0.f; int of1 = cy0 * 16 + cx1;
        float wg2 = (vx0 && vy1) ? wx0 * wy1 : 0.f; int of2 = cy1 * 16 + cx0;
        float wg3 = (vx1 && vy1) ? wx1 * wy1 : 0.f; int of3 = cy1 * 16 + cx1;
        float X2[4];
        #pragma unroll
        for (int j = 0; j < 4; ++j)
            X2[j] = vf_b[j] + vf_w[j * 36 + 0] * Xh[0] + vf_w[j * 36 + 1] * Xh[1]
                            + vf_w[j * 36 + 2] * Xh[2] + vf_w[j * 36 + 3] * Xh[3];
        const float* cmb = cm + (size_t)b * CC_ * HW_;
        #pragma unroll 8
        for (int c = 0; c < 32; ++c) {
            const float* pch = cmb + c * HW_;
            float lc = wg0 * pch[of0] + wg1 * pch[of1] + wg2 * pch[of2] + wg3 * pch[of3];
            #pragma unroll
            for (int j = 0; j < 4; ++j) X2[j] += vf_w[j * 36 + 4 + c] * lc;
        }
        float A = 0.f, Bv = 0.f, C = 0.f;
        #pragma unroll
        for (int j = 0; j < 8; ++j) {
            float Qj = fc_b[j] + fc_w[j * 4 + 0] * X2[0] + fc_w[j * 4 + 1] * X2[1]
                               + fc_w[j * 4 + 2] * X2[2] + fc_w[j * 4 + 3] * X2[3];
            A  += Qj * fc2_w[j * 2 + 0];
            Bv += Qj * fc2_w[j * 2 + 1];
            C  += Qj * fc2_b[j];
        }
        const float NLG2E = -1.44269504f;   // fold sigmoid's -log2(e) into coeffs
        ((float4*)ABC)[p] = make_float4(NLG2E * A, NLG2E * Bv, NLG2E * C, 0.f);
        ((float2*)XM)[p]  = make_float2(xr0, xr1);
    }
    gbar(cnt, gen);

    // ---- Phase C: rank-2 sigmoid attention, all 1280 blocks ----
    {
        int ms = blk & (MSPLIT_ - 1);
        int rest = blk >> 6;        // [0,20)
        int lt = rest % 5, b = rest / 5;
        // stage this block's XM chunk (80 float2) into LDS
        const float* xp = XM + 2 * ((size_t)b * L_ + ms * MCHUNK_);
        for (int i = tid; i < 2 * MCHUNK_; i += 256) xs[i] = xp[i];
        float A[4], Bv[4], C[4], S0[4], S1[4], Sp[4];
        #pragma unroll
        for (int k = 0; k < 4; ++k) {
            int l = lt * 1024 + k * 256 + tid;
            float4 abc = ((const float4*)ABC)[(size_t)b * L_ + l];
            A[k] = abc.x; Bv[k] = abc.y; C[k] = abc.z;
            S0[k] = 0.f; S1[k] = 0.f; Sp[k] = 0.f;
        }
        __syncthreads();
        #pragma unroll 4
        for (int j = 0; j < MCHUNK_; ++j) {
            float x0 = xs[2 * j], x1 = xs[2 * j + 1];   // LDS broadcast
            #pragma unroll
            for (int k = 0; k < 4; ++k) {
                float e = fexp2(fmaf(A[k], x0, fmaf(Bv[k], x1, C[k])));
                float pb = frcp(1.f + e);
                S0[k] = fmaf(pb, x0, S0[k]);
                S1[k] = fmaf(pb, x1, S1[k]);
                Sp[k] += pb;
            }
        }
        #pragma unroll
        for (int k = 0; k < 4; ++k) {
            int l = lt * 1024 + k * 256 + tid;
            ((float4*)part)[(size_t)(ms * B_ + b) * L_ + l] =
                make_float4(S0[k], S1[k], Sp[k], 0.f);
        }
    }
    gbar(cnt, gen);

    // ---- Phase D: reduce partials + V-reconstruct + trelu + fco. 80 blocks ----
    if (blk < 80) {
        int p = blk * 256 + tid;
        int b = p / L_, l = p - b * L_;
        float s0 = 0.f, s1 = 0.f, sp = 0.f;
        for (int s = 0; s < MSPLIT_; ++s) {
            float4 u = ((const float4*)part)[(size_t)(s * B_ + b) * L_ + l];
            s0 += u.x; s1 += u.y; sp += u.z;
        }
        float o0 = fco_b[0], o1 = fco_b[1];
        #pragma unroll
        for (int d = 0; d < 8; ++d) {
            float od = fc3_w[d * 2 + 0] * s0 + fc3_w[d * 2 + 1] * s1 + fc3_b[d] * sp;
            od = od > 0.5f ? od : 0.f;   // threshold_relu, TH=0.5
            o0 += fco_w[d] * od;
            o1 += fco_w[8 + d] * od;
        }
        int t = l >> 8, n = l & 255;
        out[((b * 2 + 0) * T_ + t) * N_ + n] = o0;
        out[((b * 2 + 1) * T_ + t) * N_ + n] = o1;
    }
}

extern "C" void kernel_launch(void* const* d_in, const int* in_sizes, int n_in,
                              void* d_out, int out_size, void* d_ws, size_t ws_size,
                              hipStream_t stream) {
    const float* x      = (const float*)d_in[0];
    const float* md     = (const float*)d_in[1];
    const float* w_ih   = (const float*)d_in[2];
    const float* b_ih   = (const float*)d_in[3];
    const float* b_hh   = (const float*)d_in[4];
    const float* comp_w = (const float*)d_in[5];
    const float* comp_b = (const float*)d_in[6];
    const float* vf_w   = (const float*)d_in[7];
    const float* vf_b   = (const float*)d_in[8];
    const float* fc_w   = (const float*)d_in[9];
    const float* fc_b   = (const float*)d_in[10];
    const float* fc2_w  = (const float*)d_in[11];
    const float* fc2_b  = (const float*)d_in[12];
    const float* fc3_w  = (const float*)d_in[13];
    const float* fc3_b  = (const float*)d_in[14];
    const float* fco_w  = (const float*)d_in[15];
    const float* fco_b  = (const float*)d_in[16];

    // zero the grid-barrier counters (captured as a graph memset node)
    hipMemsetAsync(d_ws, 0, 4608, stream);
    hipLaunchKernelGGL(k_fused, dim3(GRID_), dim3(256), 0, stream,
                       x, md, w_ih, b_ih, b_hh, comp_w, comp_b,
                       vf_w, vf_b, fc_w, fc_b, fc2_w, fc2_b,
                       fc3_w, fc3_b, fco_w, fco_b,
                       (float*)d_ws, (float*)d_out);
}

// Round 12
// 179.884 us; speedup vs baseline: 6.4282x; 1.5129x over previous
//
#include <hip/hip_runtime.h>
#include <math.h>

#define B_      4
#define T_      20
#define N_      256
#define L_      5120      // T_*N_
#define CC_     32
#define CMAP_   2048
#define HW_     256       // 16*16
#define GRID_   1280      // 20 groups of 64
#define MSPLIT_ 64
#define MCHUNK_ 80        // L_/MSPLIT_
#define CSPL_   32        // compress channel splits
#define CW_     64        // channels per split (CMAP_/CSPL_)

__device__ __forceinline__ float fexp2(float x) { return __builtin_amdgcn_exp2f(x); }
__device__ __forceinline__ float frcp(float x)  { return __builtin_amdgcn_rcpf(x); }
__device__ __forceinline__ float sigm(float x)  { return frcp(1.f + fexp2(-1.44269504f * x)); }
__device__ __forceinline__ float tanh_(float x) { return 1.f - 2.f * frcp(fexp2(2.88539008f * x) + 1.f); }

// ---- LLC-coherent access helpers: relaxed agent-scope atomics bypass the
// non-coherent per-XCD L2 (performed at the coherence point). Inter-phase
// data via these needs NO wbL2/inv fences (R11's 37us/barrier cost).
__device__ __forceinline__ void st_f1(float* p, float a) {
    __hip_atomic_store((unsigned*)p, __float_as_uint(a),
                       __ATOMIC_RELAXED, __HIP_MEMORY_SCOPE_AGENT);
}
__device__ __forceinline__ float ld_f1(const float* p) {
    return __uint_as_float(__hip_atomic_load((const unsigned*)p,
                       __ATOMIC_RELAXED, __HIP_MEMORY_SCOPE_AGENT));
}
__device__ __forceinline__ void st_f2(float* p, float a, float b) {
    union { float f[2]; unsigned long long u; } v; v.f[0] = a; v.f[1] = b;
    __hip_atomic_store((unsigned long long*)p, v.u,
                       __ATOMIC_RELAXED, __HIP_MEMORY_SCOPE_AGENT);
}
__device__ __forceinline__ float2 ld_f2(const float* p) {
    union { float f[2]; unsigned long long u; } v;
    v.u = __hip_atomic_load((const unsigned long long*)p,
                       __ATOMIC_RELAXED, __HIP_MEMORY_SCOPE_AGENT);
    return make_float2(v.f[0], v.f[1]);
}

// ---- grid barrier v3: zero fences, monotonic counters, block-local gen.
// __syncthreads drains each wave's stores (vmcnt0) -> data at LLC before
// lane0's relaxed arrive-add. gen flip is control-dependent on the root's
// completed RMW -> happens-before chain lives entirely at the LLC.
__device__ __forceinline__ void gbar(unsigned* cnt, unsigned* gen, unsigned my_g) {
    __syncthreads();
    if (threadIdx.x == 0) {
        int grp = blockIdx.x >> 6;   // [0,20)
        unsigned prev = __hip_atomic_fetch_add(&cnt[grp * 16], 1u,
                                               __ATOMIC_RELAXED, __HIP_MEMORY_SCOPE_AGENT);
        if (prev == 64u * (my_g + 1u) - 1u) {
            unsigned pr = __hip_atomic_fetch_add(&cnt[32 * 16], 1u,
                                                 __ATOMIC_RELAXED, __HIP_MEMORY_SCOPE_AGENT);
            if (pr == 20u * (my_g + 1u) - 1u) {
                __hip_atomic_store(gen, my_g + 1u, __ATOMIC_RELAXED, __HIP_MEMORY_SCOPE_AGENT);
            } else {
                while (__hip_atomic_load(gen, __ATOMIC_RELAXED, __HIP_MEMORY_SCOPE_AGENT) < my_g + 1u)
                    __builtin_amdgcn_s_sleep(32);
            }
        } else {
            while (__hip_atomic_load(gen, __ATOMIC_RELAXED, __HIP_MEMORY_SCOPE_AGENT) < my_g + 1u)
                __builtin_amdgcn_s_sleep(32);
        }
    }
    __syncthreads();
}

// ws float layout:
//  [0,1152)                  barrier counters/gen (memset 4608B each launch)
//  pcm  @1152    size 32*4*32*256 = 1048576
//  cm   @1049728 size 32768
//  ABC  @1082496 size 4*B*L = 81920   (float4/token, -log2e pre-scaled)
//  XM   @1164416 size 2*B*L = 40960   (float2/token)
//  part @1205376 size MSPLIT*B*L*4 = 5242880

__global__ void __launch_bounds__(256, 5) k_fused(
        const float* __restrict__ x,      const float* __restrict__ md,
        const float* __restrict__ w_ih,   const float* __restrict__ b_ih,
        const float* __restrict__ b_hh,
        const float* __restrict__ comp_w, const float* __restrict__ comp_b,
        const float* __restrict__ vf_w,   const float* __restrict__ vf_b,
        const float* __restrict__ fc_w,   const float* __restrict__ fc_b,
        const float* __restrict__ fc2_w,  const float* __restrict__ fc2_b,
        const float* __restrict__ fc3_w,  const float* __restrict__ fc3_b,
        const float* __restrict__ fco_w,  const float* __restrict__ fco_b,
        float* __restrict__ ws, float* __restrict__ out) {
    __shared__ float xs[2 * MCHUNK_];   // attn XM stage (640 B)
    unsigned* cnt = (unsigned*)ws;
    unsigned* gen = cnt + 33 * 16;
    float* pcm  = ws + 1152;
    float* cm   = pcm + CSPL_ * B_ * CC_ * HW_;
    float* ABC  = cm + B_ * CC_ * HW_;
    float* XM   = ABC + 4 * B_ * L_;
    float* part = XM + 2 * B_ * L_;

    int blk = blockIdx.x, tid = threadIdx.x;

    // ---- Phase A: compressor partials. 128 blocks (b,cs); thread = hw ----
    if (blk < B_ * CSPL_) {
        int cs = blk & (CSPL_ - 1);
        int b  = blk >> 5;
        int c0 = cs * CW_;
        const float* mp = md + ((size_t)(b * CMAP_ + c0)) * HW_ + tid;
        const float* wp = comp_w + c0;   // uniform addresses -> scalar loads
        float a[CC_];
        #pragma unroll
        for (int o = 0; o < CC_; ++o) a[o] = 0.f;
        for (int cc = 0; cc < CW_; ++cc) {
            float mv = mp[(size_t)cc * HW_];   // coalesced 1KB/wave (plain: input)
            #pragma unroll
            for (int o = 0; o < CC_; ++o)
                a[o] = fmaf(wp[o * CMAP_ + cc], mv, a[o]);
        }
        float* pp = pcm + (size_t)(cs * B_ + b) * (CC_ * HW_) + tid;
        #pragma unroll
        for (int o = 0; o < CC_; ++o) st_f1(pp + o * HW_, a[o]);   // lane-coalesced
    }
    gbar(cnt, gen, 0u);

    // ---- Phase A2: reduce 32 c-splits + bias -> cm. 128 blocks ----
    if (blk < 128) {
        int i = blk * 256 + tid;   // [0, 32768) = ((b*32+o)*256+hw)
        float s = comp_b[(i >> 8) & 31];
        #pragma unroll
        for (int ps = 0; ps < CSPL_; ++ps) s += ld_f1(pcm + ps * (B_ * CC_ * HW_) + i);
        st_f1(cm + i, s);
    }
    gbar(cnt, gen, 1u);

    // ---- Phase B: per-token LSTM + grid-sample + projections. 80 blocks ----
    if (blk < 80) {
        int p = blk * 256 + tid;   // [0, B*L)
        int b = p / L_;
        int l = p - b * L_;
        int t = l >> 8, n = l & 255;
        float x0r = x[((b * 2 + 0) * T_ + t) * N_ + n];
        float x1r = x[((b * 2 + 1) * T_ + t) * N_ + n];
        float xr0 = x0r + sinf((float)t);
        float xr1 = x1r + cosf((float)t);
        float Xh[4];
        #pragma unroll
        for (int k = 0; k < 4; ++k) {
            float ig = w_ih[(k)      * 2] * xr0 + w_ih[(k)      * 2 + 1] * xr1 + b_ih[k]      + b_hh[k];
            float gg = w_ih[(8 + k)  * 2] * xr0 + w_ih[(8 + k)  * 2 + 1] * xr1 + b_ih[8 + k]  + b_hh[8 + k];
            float og = w_ih[(12 + k) * 2] * xr0 + w_ih[(12 + k) * 2 + 1] * xr1 + b_ih[12 + k] + b_hh[12 + k];
            float c = sigm(ig) * tanh_(gg);
            Xh[k] = sigm(og) * tanh_(c);
        }
        // bilinear grid-sample on RAW coords (align_corners=False, zero pad)
        float ix = x0r * 0.03125f - 0.5f;
        float iy = x1r * 0.03125f - 0.5f;
        float x0f = floorf(ix), y0f = floorf(iy);
        float wx1 = ix - x0f, wx0 = 1.f - wx1;
        float wy1 = iy - y0f, wy0 = 1.f - wy1;
        int x0 = (int)x0f, y0 = (int)y0f;
        int x1 = x0 + 1, y1 = y0 + 1;
        bool vx0 = (x0 >= 0) && (x0 <= 15), vx1 = (x1 >= 0) && (x1 <= 15);
        bool vy0 = (y0 >= 0) && (y0 <= 15), vy1 = (y1 >= 0) && (y1 <= 15);
        int cx0 = min(max(x0, 0), 15), cx1 = min(max(x1, 0), 15);
        int cy0 = min(max(y0, 0), 15), cy1 = min(max(y1, 0), 15);
        float wg0 = (vx0 && vy0) ? wx0 * wy0 : 0.f; int of0 = cy0 * 16 + cx0;
        float wg1 = (vx1 && vy0) ? wx1 * wy0 : 0.f; int of1 = cy0 * 16 + cx1;
        float wg2 = (vx0 && vy1) ? wx0 * wy1 : 0.f; int of2 = cy1 * 16 + cx0;
        float wg3 = (vx1 && vy1) ? wx1 * wy1 : 0.f; int of3 = cy1 * 16 + cx1;
        float X2[4];
        #pragma unroll
        for (int j = 0; j < 4; ++j)
            X2[j] = vf_b[j] + vf_w[j * 36 + 0] * Xh[0] + vf_w[j * 36 + 1] * Xh[1]
                            + vf_w[j * 36 + 2] * Xh[2] + vf_w[j * 36 + 3] * Xh[3];
        const float* cmb = cm + (size_t)b * CC_ * HW_;
        #pragma unroll 8
        for (int c = 0; c < 32; ++c) {
            const float* pch = cmb + c * HW_;
            float lc = wg0 * ld_f1(pch + of0) + wg1 * ld_f1(pch + of1)
                     + wg2 * ld_f1(pch + of2) + wg3 * ld_f1(pch + of3);
            #pragma unroll
            for (int j = 0; j < 4; ++j) X2[j] += vf_w[j * 36 + 4 + c] * lc;
        }
        float A = 0.f, Bv = 0.f, C = 0.f;
        #pragma unroll
        for (int j = 0; j < 8; ++j) {
            float Qj = fc_b[j] + fc_w[j * 4 + 0] * X2[0] + fc_w[j * 4 + 1] * X2[1]
                               + fc_w[j * 4 + 2] * X2[2] + fc_w[j * 4 + 3] * X2[3];
            A  += Qj * fc2_w[j * 2 + 0];
            Bv += Qj * fc2_w[j * 2 + 1];
            C  += Qj * fc2_b[j];
        }
        const float NLG2E = -1.44269504f;   // fold sigmoid's -log2(e) into coeffs
        st_f2(ABC + 4 * (size_t)p,     NLG2E * A, NLG2E * Bv);
        st_f2(ABC + 4 * (size_t)p + 2, NLG2E * C, 0.f);
        st_f2(XM  + 2 * (size_t)p,     xr0, xr1);
    }
    gbar(cnt, gen, 2u);

    // ---- Phase C: rank-2 sigmoid attention, all 1280 blocks ----
    {
        int ms = blk & (MSPLIT_ - 1);
        int rest = blk >> 6;        // [0,20)
        int lt = rest % 5, b = rest / 5;
        if (tid < MCHUNK_) {        // stage 80 float2 into LDS
            float2 v = ld_f2(XM + 2 * ((size_t)b * L_ + ms * MCHUNK_ + tid));
            xs[2 * tid] = v.x; xs[2 * tid + 1] = v.y;
        }
        float A[4], Bv[4], C[4], S0[4], S1[4], Sp[4];
        #pragma unroll
        for (int k = 0; k < 4; ++k) {
            int l = lt * 1024 + k * 256 + tid;
            float2 ab = ld_f2(ABC + 4 * ((size_t)b * L_ + l));
            float2 cz = ld_f2(ABC + 4 * ((size_t)b * L_ + l) + 2);
            A[k] = ab.x; Bv[k] = ab.y; C[k] = cz.x;
            S0[k] = 0.f; S1[k] = 0.f; Sp[k] = 0.f;
        }
        __syncthreads();
        #pragma unroll 4
        for (int j = 0; j < MCHUNK_; ++j) {
            float x0 = xs[2 * j], x1 = xs[2 * j + 1];   // LDS broadcast
            #pragma unroll
            for (int k = 0; k < 4; ++k) {
                float e = fexp2(fmaf(A[k], x0, fmaf(Bv[k], x1, C[k])));
                float pb = frcp(1.f + e);
                S0[k] = fmaf(pb, x0, S0[k]);
                S1[k] = fmaf(pb, x1, S1[k]);
                Sp[k] += pb;
            }
        }
        #pragma unroll
        for (int k = 0; k < 4; ++k) {
            int l = lt * 1024 + k * 256 + tid;
            float* pr = part + 4 * ((size_t)(ms * B_ + b) * L_ + l);
            st_f2(pr,     S0[k], S1[k]);
            st_f2(pr + 2, Sp[k], 0.f);
        }
    }
    gbar(cnt, gen, 3u);

    // ---- Phase D: reduce partials + V-reconstruct + trelu + fco. 80 blocks ----
    if (blk < 80) {
        int p = blk * 256 + tid;
        int b = p / L_, l = p - b * L_;
        float s0 = 0.f, s1 = 0.f, sp = 0.f;
        for (int s = 0; s < MSPLIT_; ++s) {
            const float* pr = part + 4 * ((size_t)(s * B_ + b) * L_ + l);
            float2 u = ld_f2(pr);
            float2 v = ld_f2(pr + 2);
            s0 += u.x; s1 += u.y; sp += v.x;
        }
        float o0 = fco_b[0], o1 = fco_b[1];
        #pragma unroll
        for (int d = 0; d < 8; ++d) {
            float od = fc3_w[d * 2 + 0] * s0 + fc3_w[d * 2 + 1] * s1 + fc3_b[d] * sp;
            od = od > 0.5f ? od : 0.f;   // threshold_relu, TH=0.5
            o0 += fco_w[d] * od;
            o1 += fco_w[8 + d] * od;
        }
        int t = l >> 8, n = l & 255;
        out[((b * 2 + 0) * T_ + t) * N_ + n] = o0;
        out[((b * 2 + 1) * T_ + t) * N_ + n] = o1;
    }
}

extern "C" void kernel_launch(void* const* d_in, const int* in_sizes, int n_in,
                              void* d_out, int out_size, void* d_ws, size_t ws_size,
                              hipStream_t stream) {
    const float* x      = (const float*)d_in[0];
    const float* md     = (const float*)d_in[1];
    const float* w_ih   = (const float*)d_in[2];
    const float* b_ih   = (const float*)d_in[3];
    const float* b_hh   = (const float*)d_in[4];
    const float* comp_w = (const float*)d_in[5];
    const float* comp_b = (const float*)d_in[6];
    const float* vf_w   = (const float*)d_in[7];
    const float* vf_b   = (const float*)d_in[8];
    const float* fc_w   = (const float*)d_in[9];
    const float* fc_b   = (const float*)d_in[10];
    const float* fc2_w  = (const float*)d_in[11];
    const float* fc2_b  = (const float*)d_in[12];
    const float* fc3_w  = (const float*)d_in[13];
    const float* fc3_b  = (const float*)d_in[14];
    const float* fco_w  = (const float*)d_in[15];
    const float* fco_b  = (const float*)d_in[16];

    // zero the grid-barrier counters (captured as a graph memset node)
    hipMemsetAsync(d_ws, 0, 4608, stream);
    hipLaunchKernelGGL(k_fused, dim3(GRID_), dim3(256), 0, stream,
                       x, md, w_ih, b_ih, b_hh, comp_w, comp_b,
                       vf_w, vf_b, fc_w, fc_b, fc2_w, fc2_b,
                       fc3_w, fc3_b, fco_w, fco_b,
                       (float*)d_ws, (float*)d_out);
}